// Round 6
// baseline (10000.842 us; speedup 1.0000x reference)
//
#include <hip/hip_runtime.h>

// Problem constants
#define BB   64      // batch
#define TT   256     // seq len
#define II   768     // input dim
#define HH   384     // hidden per direction
#define DD   768     // 2*HH
#define G3   1152    // 3*HH
#define G6   2304    // both directions' gates

#define TILE 128
#define BK   16

typedef unsigned long long u64t;

// ---------------------------------------------------------------------------
// GEMM: gxT[t][n][b] = bias[n] + sum_k X[t,b,k] * W[n,k]   (n in [0,2304))
// Transposed output (n-major, batch-minor).
// ---------------------------------------------------------------------------
__global__ __launch_bounds__(256) void gemm_gx(
    const float* __restrict__ X, int xmode,
    const float* __restrict__ wf, const float* __restrict__ wb,
    const float* __restrict__ bif, const float* __restrict__ bib,
    float* __restrict__ gx)
{
    __shared__ float As[BK][TILE + 4];
    __shared__ float Bs[BK][TILE + 4];
    const int tid = threadIdx.x;
    const int tx = tid & 15, ty = tid >> 4;
    const int m0 = blockIdx.y * TILE;
    const int n0 = blockIdx.x * TILE;

    float acc[8][8];
#pragma unroll
    for (int i = 0; i < 8; i++)
#pragma unroll
        for (int j = 0; j < 8; j++) acc[i][j] = 0.f;

    for (int k0 = 0; k0 < 768; k0 += BK) {
#pragma unroll
        for (int l = 0; l < 2; l++) {
            int id = tid + l * 256;          // 0..511
            int r  = id >> 2;                // 0..127
            int kq = (id & 3) * 4;
            int m  = m0 + r;
            const float* src;
            if (xmode == 0) {
                int b = m & 63, t = m >> 6;
                src = X + (size_t)b * (TT * II) + (size_t)t * II + k0 + kq;
            } else {
                src = X + (size_t)m * 768 + k0 + kq;
            }
            float4 v = *(const float4*)src;
            As[kq + 0][r] = v.x; As[kq + 1][r] = v.y;
            As[kq + 2][r] = v.z; As[kq + 3][r] = v.w;
        }
#pragma unroll
        for (int l = 0; l < 2; l++) {
            int id = tid + l * 256;
            int r  = id >> 2;
            int kq = (id & 3) * 4;
            int n  = n0 + r;
            const float* wsrc = (n < G3) ? (wf + (size_t)n * 768)
                                         : (wb + (size_t)(n - G3) * 768);
            float4 v = *(const float4*)(wsrc + k0 + kq);
            Bs[kq + 0][r] = v.x; Bs[kq + 1][r] = v.y;
            Bs[kq + 2][r] = v.z; Bs[kq + 3][r] = v.w;
        }
        __syncthreads();
#pragma unroll
        for (int kk = 0; kk < BK; ++kk) {
            float av[8], bv[8];
            *(float4*)&av[0] = *(const float4*)&As[kk][ty * 8];
            *(float4*)&av[4] = *(const float4*)&As[kk][ty * 8 + 4];
            *(float4*)&bv[0] = *(const float4*)&Bs[kk][tx * 8];
            *(float4*)&bv[4] = *(const float4*)&Bs[kk][tx * 8 + 4];
#pragma unroll
            for (int i = 0; i < 8; i++)
#pragma unroll
                for (int j = 0; j < 8; j++)
                    acc[i][j] = fmaf(av[i], bv[j], acc[i][j]);
        }
        __syncthreads();
    }

#pragma unroll
    for (int i = 0; i < 8; i++) {
        int m = m0 + ty * 8 + i;
        int t = m >> 6, b = m & 63;
        float* dst = gx + ((size_t)t * G6 + n0 + tx * 8) * 64 + b;
#pragma unroll
        for (int j = 0; j < 8; j++) {
            int n = n0 + tx * 8 + j;
            float bias = (n < G3) ? bif[n] : bib[n - G3];
            dst[(size_t)j * 64] = acc[i][j] + bias;
        }
    }
}

// ---------------------------------------------------------------------------
// Recurrent kernel v7: flag-validated fp32 h exchange.
//
// h values: plain fp32, [dir][pp][k4=96][b=64][e=4]  (column c = k4*4+e),
// published with relaxed agent-scope stores. Validity: per-column flags
// flags[dir][pp][384]; producer wave does {store 64 values; s_waitcnt
// vmcnt(0); lane0 stores flag=s+1} (release). Consumers spin on 6 coalesced
// flag dwords, then load their 24-KB k-chunk as u64 agent-scope atomic
// loads (compiler-managed waitcnts, pipelined with the FMAs).
//
// 192 WGs x 256 thr: WG 0..95 fwd, 96..191 bwd; 4 columns/WG; wave w covers
// k-chunk [w*96,(w+1)*96) for all 12 (col,gate) dots, finalizes col c0+w
// after LDS partial reduce (one __syncthreads per step).
// ---------------------------------------------------------------------------
__global__ __launch_bounds__(256) void recur7(
    const float* __restrict__ gxT,  // [T][2304][64] (b_ih already added)
    const float* __restrict__ whf, const float* __restrict__ whb,
    const float* __restrict__ bhf, const float* __restrict__ bhb,
    float* __restrict__ hv,         // [2dir][2pp][96][64][4] fp32, zeroed
    unsigned* __restrict__ hf,      // [2dir][2pp][384] flags, zeroed
    float* __restrict__ out)        // [T][B][768]
{
    __shared__ float part[2][4][12][64];    // [pp][wave][col*3+gate][lane]

    const int bid  = blockIdx.x;            // 0..191
    const int dir  = bid / 96;
    const int k4g  = bid % 96;              // my WG's k4 group (cols k4g*4..+3)
    const int c0   = k4g * 4;
    const int tid  = threadIdx.x;
    const int lane = tid & 63;              // batch
    const int w    = __builtin_amdgcn_readfirstlane(tid >> 6);  // wave 0..3
    const int c    = c0 + w;                // column this wave finalizes

    const float* wh = dir ? whb : whf;
    const float* bh = dir ? bhb : bhf;

    // 12 uniform weight row pointers, offset to this wave's k-chunk
    const float* wpp[12];
#pragma unroll
    for (int cc = 0; cc < 4; cc++)
#pragma unroll
        for (int g = 0; g < 3; g++)
            wpp[cc * 3 + g] = wh + (size_t)(g * HH + c0 + cc) * HH + w * 96;

    const float bhr = bh[c], bhz = bh[HH + c], bhn = bh[2 * HH + c];

    // per-(dir,pp) regions
    float*    hv0 = hv + (size_t)dir * 2 * 24576;
    unsigned* hf0 = hf + (size_t)dir * 2 * 384;

    float hprev = 0.f;

    for (int s = 0; s < TT; s++) {
        const int t  = dir ? (TT - 1 - s) : s;
        const int pp = s & 1;
        const float*    hvp = hv0 + (size_t)pp * 24576;
        const unsigned* hfp = hf0 + (size_t)pp * 384;
        const unsigned  want = (unsigned)s;

        // gx loads (normal path, compiler-managed): issue before the spin
        const float* gp = gxT + ((size_t)t * G6 + dir * G3 + c) * 64 + lane;
        float gr = gp[0];
        float gz = gp[(size_t)HH * 64];
        float gn = gp[(size_t)2 * HH * 64];

        // flag spin: 6 coalesced dwords cover all 384 columns
        while (true) {
            unsigned f0 = __hip_atomic_load(hfp + lane,       __ATOMIC_RELAXED, __HIP_MEMORY_SCOPE_AGENT);
            unsigned f1 = __hip_atomic_load(hfp + lane + 64,  __ATOMIC_RELAXED, __HIP_MEMORY_SCOPE_AGENT);
            unsigned f2 = __hip_atomic_load(hfp + lane + 128, __ATOMIC_RELAXED, __HIP_MEMORY_SCOPE_AGENT);
            unsigned f3 = __hip_atomic_load(hfp + lane + 192, __ATOMIC_RELAXED, __HIP_MEMORY_SCOPE_AGENT);
            unsigned f4 = __hip_atomic_load(hfp + lane + 256, __ATOMIC_RELAXED, __HIP_MEMORY_SCOPE_AGENT);
            unsigned f5 = __hip_atomic_load(hfp + lane + 320, __ATOMIC_RELAXED, __HIP_MEMORY_SCOPE_AGENT);
            bool ok = (f0 >= want) && (f1 >= want) && (f2 >= want) &&
                      (f3 >= want) && (f4 >= want) && (f5 >= want);
            if (__all(ok)) break;
            __builtin_amdgcn_s_sleep(1);
        }

        // value load + FMA: 24 groups of 16 B per lane (u64 pairs), unrolled
        // so the compiler pipelines loads ahead of the FMA stream.
        float acc[12];
#pragma unroll
        for (int i = 0; i < 12; i++) acc[i] = 0.f;

        const u64t* hv64 = (const u64t*)hvp;
#pragma unroll
        for (int g = 0; g < 24; g++) {
            const size_t off = (size_t)(w * 24 + g) * 128 + lane * 2;
            u64t p0 = __hip_atomic_load(hv64 + off,     __ATOMIC_RELAXED, __HIP_MEMORY_SCOPE_AGENT);
            u64t p1 = __hip_atomic_load(hv64 + off + 1, __ATOMIC_RELAXED, __HIP_MEMORY_SCOPE_AGENT);
            float v0 = __uint_as_float((unsigned)p0);
            float v1 = __uint_as_float((unsigned)(p0 >> 32));
            float v2 = __uint_as_float((unsigned)p1);
            float v3 = __uint_as_float((unsigned)(p1 >> 32));
#pragma unroll
            for (int cg = 0; cg < 12; cg++) {
                const float* wrow = wpp[cg] + g * 4;
                acc[cg] = fmaf(v0, wrow[0], acc[cg]);
                acc[cg] = fmaf(v1, wrow[1], acc[cg]);
                acc[cg] = fmaf(v2, wrow[2], acc[cg]);
                acc[cg] = fmaf(v3, wrow[3], acc[cg]);
            }
        }

        // partial reduce through LDS (one barrier per step)
#pragma unroll
        for (int cg = 0; cg < 12; cg++)
            part[pp][w][cg][lane] = acc[cg];
        __syncthreads();

        const int d0 = w * 3;
        float ar = part[pp][0][d0 + 0][lane] + part[pp][1][d0 + 0][lane]
                 + part[pp][2][d0 + 0][lane] + part[pp][3][d0 + 0][lane];
        float az = part[pp][0][d0 + 1][lane] + part[pp][1][d0 + 1][lane]
                 + part[pp][2][d0 + 1][lane] + part[pp][3][d0 + 1][lane];
        float an = part[pp][0][d0 + 2][lane] + part[pp][1][d0 + 2][lane]
                 + part[pp][2][d0 + 2][lane] + part[pp][3][d0 + 2][lane];

        float ghr = ar + bhr, ghz = az + bhz, ghn = an + bhn;
        float rr  = 1.f / (1.f + expf(-(gr + ghr)));
        float zz  = 1.f / (1.f + expf(-(gz + ghz)));
        float nn  = tanhf(gn + rr * ghn);
        float hnew = (1.f - zz) * nn + zz * hprev;
        hprev = hnew;

        // publish value (relaxed), release via vmcnt drain, then flag
        {
            float* hvn = hv0 + (size_t)(pp ^ 1) * 24576;
            __hip_atomic_store(hvn + (size_t)k4g * 256 + lane * 4 + w, hnew,
                               __ATOMIC_RELAXED, __HIP_MEMORY_SCOPE_AGENT);
            asm volatile("s_waitcnt vmcnt(0)" ::: "memory");
            if (lane == 0) {
                unsigned* hfn = hf0 + (size_t)(pp ^ 1) * 384;
                __hip_atomic_store(hfn + c, (unsigned)(s + 1),
                                   __ATOMIC_RELAXED, __HIP_MEMORY_SCOPE_AGENT);
            }
        }
        // big output tensor: normal store (flushed at kernel end)
        out[(size_t)t * (BB * DD) + (size_t)lane * DD + dir * HH + c] = hnew;
    }
}

// ---------------------------------------------------------------------------
// Attention logits: logits[b][t] += sum_n tanh(hidden[t,b,:]·fcw[n,:] + fcb[n]) * upw[n]
// ---------------------------------------------------------------------------
__global__ __launch_bounds__(256) void attn_logits(
    const float* __restrict__ Xh,   // hidden [T*B][768]
    const float* __restrict__ fcw,  // [768][768]
    const float* __restrict__ fcb, const float* __restrict__ upw,
    float* __restrict__ logits)     // [B][T]
{
    __shared__ float As[BK][TILE + 4];
    __shared__ float Bs[BK][TILE + 4];
    __shared__ float red[TILE][17];
    const int tid = threadIdx.x;
    const int tx = tid & 15, ty = tid >> 4;
    const int m0 = blockIdx.y * TILE;
    const int n0 = blockIdx.x * TILE;

    float acc[8][8];
#pragma unroll
    for (int i = 0; i < 8; i++)
#pragma unroll
        for (int j = 0; j < 8; j++) acc[i][j] = 0.f;

    for (int k0 = 0; k0 < 768; k0 += BK) {
#pragma unroll
        for (int l = 0; l < 2; l++) {
            int id = tid + l * 256;
            int r  = id >> 2;
            int kq = (id & 3) * 4;
            float4 v = *(const float4*)(Xh + (size_t)(m0 + r) * 768 + k0 + kq);
            As[kq + 0][r] = v.x; As[kq + 1][r] = v.y;
            As[kq + 2][r] = v.z; As[kq + 3][r] = v.w;
        }
#pragma unroll
        for (int l = 0; l < 2; l++) {
            int id = tid + l * 256;
            int r  = id >> 2;
            int kq = (id & 3) * 4;
            float4 v = *(const float4*)(fcw + (size_t)(n0 + r) * 768 + k0 + kq);
            Bs[kq + 0][r] = v.x; Bs[kq + 1][r] = v.y;
            Bs[kq + 2][r] = v.z; Bs[kq + 3][r] = v.w;
        }
        __syncthreads();
#pragma unroll
        for (int kk = 0; kk < BK; ++kk) {
            float av[8], bv[8];
            *(float4*)&av[0] = *(const float4*)&As[kk][ty * 8];
            *(float4*)&av[4] = *(const float4*)&As[kk][ty * 8 + 4];
            *(float4*)&bv[0] = *(const float4*)&Bs[kk][tx * 8];
            *(float4*)&bv[4] = *(const float4*)&Bs[kk][tx * 8 + 4];
#pragma unroll
            for (int i = 0; i < 8; i++)
#pragma unroll
                for (int j = 0; j < 8; j++)
                    acc[i][j] = fmaf(av[i], bv[j], acc[i][j]);
        }
        __syncthreads();
    }

#pragma unroll
    for (int i = 0; i < 8; i++) {
        float p = 0.f;
#pragma unroll
        for (int jj = 0; jj < 8; jj++) {
            int n = n0 + tx * 8 + jj;
            p += tanhf(acc[i][jj] + fcb[n]) * upw[n];
        }
        red[ty * 8 + i][tx] = p;
    }
    __syncthreads();
    if (tid < TILE) {
        float s = 0.f;
#pragma unroll
        for (int x = 0; x < 16; x++) s += red[tid][x];
        int m = m0 + tid;
        int t = m >> 6, b = m & 63;
        atomicAdd(&logits[(size_t)b * TT + t], s);
    }
}

// ---------------------------------------------------------------------------
// Softmax over T per batch + weighted pooling
// ---------------------------------------------------------------------------
__global__ __launch_bounds__(256) void softmax_pool(
    const float* __restrict__ logits, const float* __restrict__ upwb,
    const float* __restrict__ hidden, float* __restrict__ out)
{
    const int b = blockIdx.x, tid = threadIdx.x;
    __shared__ float sa[256];
    __shared__ float red[256];

    float l = logits[(size_t)b * TT + tid] + upwb[0];
    red[tid] = l; __syncthreads();
    for (int s = 128; s > 0; s >>= 1) {
        if (tid < s) red[tid] = fmaxf(red[tid], red[tid + s]);
        __syncthreads();
    }
    float mx = red[0];
    __syncthreads();
    float e = expf(l - mx);
    sa[tid] = e; red[tid] = e; __syncthreads();
    for (int s = 128; s > 0; s >>= 1) {
        if (tid < s) red[tid] += red[tid + s];
        __syncthreads();
    }
    float inv = 1.f / red[0];

    float o0 = 0.f, o1 = 0.f, o2 = 0.f;
    for (int t = 0; t < TT; t++) {
        float a = sa[t] * inv;
        const float* hp = hidden + (size_t)t * (BB * DD) + (size_t)b * DD;
        o0 = fmaf(a, hp[tid],       o0);
        o1 = fmaf(a, hp[tid + 256], o1);
        o2 = fmaf(a, hp[tid + 512], o2);
    }
    out[(size_t)b * DD + tid]       = o0;
    out[(size_t)b * DD + tid + 256] = o1;
    out[(size_t)b * DD + tid + 512] = o2;
}

// ---------------------------------------------------------------------------
extern "C" void kernel_launch(void* const* d_in, const int* in_sizes, int n_in,
                              void* d_out, int out_size, void* d_ws, size_t ws_size,
                              hipStream_t stream)
{
    const float* S        = (const float*)d_in[0];
    const float* w_ih_l0f = (const float*)d_in[1];
    const float* w_hh_l0f = (const float*)d_in[2];
    const float* b_ih_l0f = (const float*)d_in[3];
    const float* b_hh_l0f = (const float*)d_in[4];
    const float* w_ih_l0b = (const float*)d_in[5];
    const float* w_hh_l0b = (const float*)d_in[6];
    const float* b_ih_l0b = (const float*)d_in[7];
    const float* b_hh_l0b = (const float*)d_in[8];
    const float* w_ih_l1f = (const float*)d_in[9];
    const float* w_hh_l1f = (const float*)d_in[10];
    const float* b_ih_l1f = (const float*)d_in[11];
    const float* b_hh_l1f = (const float*)d_in[12];
    const float* w_ih_l1b = (const float*)d_in[13];
    const float* w_hh_l1b = (const float*)d_in[14];
    const float* b_ih_l1b = (const float*)d_in[15];
    const float* b_hh_l1b = (const float*)d_in[16];
    const float* fc_w     = (const float*)d_in[17];
    const float* fc_b     = (const float*)d_in[18];
    const float* upw_w    = (const float*)d_in[19];
    const float* upw_b    = (const float*)d_in[20];

    // workspace layout (floats)
    float* gxT     = (float*)d_ws;                       // 256*2304*64
    float* buf2    = gxT  + (size_t)TT * G6 * BB;        // 256*64*768
    float* hv      = buf2 + (size_t)TT * BB * DD;        // 2*2*96*64*4 = 98304
    unsigned* hfl  = (unsigned*)(hv + 98304);            // 2*2*384     = 1536
    float* logits  = (float*)(hfl + 1536);               // 64*256      = 16384

    // zero h values + flags + logits (contiguous region)
    hipMemsetAsync(hv, 0, (size_t)(98304 + 1536 + 16384) * 4, stream);

    // layer 0 input gates
    gemm_gx<<<dim3(18, 128), 256, 0, stream>>>(S, 0, w_ih_l0f, w_ih_l0b,
                                               b_ih_l0f, b_ih_l0b, gxT);
    // layer 0 recurrence -> buf2
    {
        void* args[] = {(void*)&gxT, (void*)&w_hh_l0f, (void*)&w_hh_l0b,
                        (void*)&b_hh_l0f, (void*)&b_hh_l0b, (void*)&hv,
                        (void*)&hfl, (void*)&buf2};
        hipLaunchCooperativeKernel((const void*)recur7, dim3(192), dim3(256),
                                   args, 0, stream);
    }
    // re-zero h values + flags for layer 1
    hipMemsetAsync(hv, 0, (size_t)(98304 + 1536) * 4, stream);

    // layer 1 input gates (from buf2)
    gemm_gx<<<dim3(18, 128), 256, 0, stream>>>(buf2, 1, w_ih_l1f, w_ih_l1b,
                                               b_ih_l1f, b_ih_l1b, gxT);
    // layer 1 recurrence -> buf2
    {
        void* args[] = {(void*)&gxT, (void*)&w_hh_l1f, (void*)&w_hh_l1b,
                        (void*)&b_hh_l1f, (void*)&b_hh_l1b, (void*)&hv,
                        (void*)&hfl, (void*)&buf2};
        hipLaunchCooperativeKernel((const void*)recur7, dim3(192), dim3(256),
                                   args, 0, stream);
    }
    // attention logits + pooling
    attn_logits<<<dim3(6, 128), 256, 0, stream>>>(buf2, fc_w, fc_b, upw_w, logits);
    softmax_pool<<<64, 256, 0, stream>>>(logits, upw_b, buf2, (float*)d_out);
}

// Round 8
// 9999.802 us; speedup vs baseline: 1.0001x; 1.0001x over previous
//
#include <hip/hip_runtime.h>

// Problem constants
#define BB   64      // batch
#define TT   256     // seq len
#define II   768     // input dim
#define HH   384     // hidden per direction
#define DD   768     // 2*HH
#define G3   1152    // 3*HH
#define G6   2304    // both directions' gates

#define TILE 128
#define BK   16

typedef unsigned long long u64t;

// ---------------------------------------------------------------------------
// GEMM: gxT[t][n][b] = bias[n] + sum_k X[t,b,k] * W[n,k]   (n in [0,2304))
// Transposed output (n-major, batch-minor): recurrence reads coalesced rows.
// xmode 0: X = Sentences [B][T][768]; xmode 1: X = [T*B][768] row-major.
// ---------------------------------------------------------------------------
__global__ __launch_bounds__(256) void gemm_gx(
    const float* __restrict__ X, int xmode,
    const float* __restrict__ wf, const float* __restrict__ wb,
    const float* __restrict__ bif, const float* __restrict__ bib,
    float* __restrict__ gx)
{
    __shared__ float As[BK][TILE + 4];
    __shared__ float Bs[BK][TILE + 4];
    const int tid = threadIdx.x;
    const int tx = tid & 15, ty = tid >> 4;
    const int m0 = blockIdx.y * TILE;
    const int n0 = blockIdx.x * TILE;

    float acc[8][8];
#pragma unroll
    for (int i = 0; i < 8; i++)
#pragma unroll
        for (int j = 0; j < 8; j++) acc[i][j] = 0.f;

    for (int k0 = 0; k0 < 768; k0 += BK) {
#pragma unroll
        for (int l = 0; l < 2; l++) {
            int id = tid + l * 256;          // 0..511
            int r  = id >> 2;                // 0..127
            int kq = (id & 3) * 4;
            int m  = m0 + r;
            const float* src;
            if (xmode == 0) {
                int b = m & 63, t = m >> 6;
                src = X + (size_t)b * (TT * II) + (size_t)t * II + k0 + kq;
            } else {
                src = X + (size_t)m * 768 + k0 + kq;
            }
            float4 v = *(const float4*)src;
            As[kq + 0][r] = v.x; As[kq + 1][r] = v.y;
            As[kq + 2][r] = v.z; As[kq + 3][r] = v.w;
        }
#pragma unroll
        for (int l = 0; l < 2; l++) {
            int id = tid + l * 256;
            int r  = id >> 2;
            int kq = (id & 3) * 4;
            int n  = n0 + r;
            const float* wsrc = (n < G3) ? (wf + (size_t)n * 768)
                                         : (wb + (size_t)(n - G3) * 768);
            float4 v = *(const float4*)(wsrc + k0 + kq);
            Bs[kq + 0][r] = v.x; Bs[kq + 1][r] = v.y;
            Bs[kq + 2][r] = v.z; Bs[kq + 3][r] = v.w;
        }
        __syncthreads();
#pragma unroll
        for (int kk = 0; kk < BK; ++kk) {
            float av[8], bv[8];
            *(float4*)&av[0] = *(const float4*)&As[kk][ty * 8];
            *(float4*)&av[4] = *(const float4*)&As[kk][ty * 8 + 4];
            *(float4*)&bv[0] = *(const float4*)&Bs[kk][tx * 8];
            *(float4*)&bv[4] = *(const float4*)&Bs[kk][tx * 8 + 4];
#pragma unroll
            for (int i = 0; i < 8; i++)
#pragma unroll
                for (int j = 0; j < 8; j++)
                    acc[i][j] = fmaf(av[i], bv[j], acc[i][j]);
        }
        __syncthreads();
    }

#pragma unroll
    for (int i = 0; i < 8; i++) {
        int m = m0 + ty * 8 + i;
        int t = m >> 6, b = m & 63;
        float* dst = gx + ((size_t)t * G6 + n0 + tx * 8) * 64 + b;
#pragma unroll
        for (int j = 0; j < 8; j++) {
            int n = n0 + tx * 8 + j;
            float bias = (n < G3) ? bif[n] : bib[n - G3];
            dst[(size_t)j * 64] = acc[i][j] + bias;
        }
    }
}

// ---------------------------------------------------------------------------
// Recurrent kernel v9: v5's single-phase self-tagged exchange, with
// (a) 8-bit step tag embedded in the LOW MANTISSA BITS of each fp32 h
//     (4 B/elem, dword-atomic, rel err <= 2^-16), and
// (b) 96 WGs (48/dir, 8 cols each) -> h broadcast 9.4 MB/step (4x cut).
//
// Layout (per dir,pp): h[k2=192][b=64][2] dwords; element (c,b) at dword
// (c>>1)*128 + b*2 + (c&1). Consumers load u64s (2 tagged values, coalesced)
// via relaxed agent-scope atomics and retry until all tags == s&0xFF.
// Producers publish bits=(h&0xFFFFFF00)|((s+1)&0xFF) per dword (atomic).
// Race-free: a WG's writes into buffer pn at step s occur only after its
// waves validated ALL tags==s (i.e. every WG published step s-1, which is
// after every WG finished reading pn at step s-1). One __syncthreads/step
// (double-buffered LDS partial reduce, 4-wave k-split).
// ---------------------------------------------------------------------------
__global__ __launch_bounds__(256) void recur9(
    const float* __restrict__ gxT,  // [T][2304][64] (b_ih already added)
    const float* __restrict__ whf, const float* __restrict__ whb,
    const float* __restrict__ bhf, const float* __restrict__ bhb,
    unsigned* __restrict__ hv,      // [2dir][2pp][192][64][2] dwords, zeroed
    float* __restrict__ out)        // [T][B][768]
{
    __shared__ float part[2][4][6][64][4];   // [pp][w][cg/4][b][cg&3] 49152 B

    const int bid  = blockIdx.x;             // 0..95
    const int dir  = bid / 48;
    const int c0   = (bid % 48) * 8;         // 8 columns per WG
    const int tid  = threadIdx.x;
    const int lane = tid & 63;               // batch (consumer role)
    const int w    = __builtin_amdgcn_readfirstlane(tid >> 6);  // wave 0..3

    const float* wh = dir ? whb : whf;
    const float* bh = dir ? bhb : bhf;

    // 24 wave-uniform weight row pointers, offset to this wave's k-chunk
    const float* wp[24];
#pragma unroll
    for (int cc = 0; cc < 8; cc++)
#pragma unroll
        for (int g = 0; g < 3; g++)
            wp[cc * 3 + g] = wh + (size_t)(g * HH + c0 + cc) * HH + w * 96;

    // finalize role: thread handles (b=fb, cols c0+cl0 and c0+cl0+4)
    const int fb  = tid & 63;
    const int cl0 = tid >> 6;                // 0..3
    float bR[2], bZ[2], bN[2], hprev[2];
#pragma unroll
    for (int i = 0; i < 2; i++) {
        int c = c0 + cl0 + i * 4;
        bR[i] = bh[c]; bZ[i] = bh[HH + c]; bN[i] = bh[2 * HH + c];
        hprev[i] = 0.f;
    }

#pragma unroll 1
    for (int s = 0; s < TT; ++s) {
        const int t  = dir ? (TT - 1 - s) : s;
        const int pp = s & 1, pn = pp ^ 1;
        const u64t*  hr  = (const u64t*)hv + (size_t)(dir * 2 + pp) * 12288;
        unsigned*    hwN = hv + (size_t)(dir * 2 + pn) * 24576;
        const unsigned want8 = (unsigned)s & 0xFFu;
        const unsigned tagp  = (unsigned)(s + 1) & 0xFFu;

        // gx prefetch for my 2 finalize outputs (plain loads, L2 path)
        float gr[2], gz[2], gn_[2];
        {
            const float* gA = gxT + ((size_t)t * G6 + dir * G3) * 64 + fb;
#pragma unroll
            for (int i = 0; i < 2; i++) {
                int c = c0 + cl0 + i * 4;
                gr[i]  = gA[(size_t)(0 * HH + c) * 64];
                gz[i]  = gA[(size_t)(1 * HH + c) * 64];
                gn_[i] = gA[(size_t)(2 * HH + c) * 64];
            }
        }

        // ---- consume: 3 blocks x 16 u64 (32 k each), retry until tags match
        float acc[24];
#pragma unroll
        for (int i = 0; i < 24; i++) acc[i] = 0.f;

#pragma unroll 1
        for (int blk = 0; blk < 3; ++blk) {
            const int k2b = w * 48 + blk * 16;
            u64t v[16];
            while (true) {
#pragma unroll
                for (int j = 0; j < 16; ++j)
                    v[j] = __hip_atomic_load(hr + (size_t)(k2b + j) * 64 + lane,
                                             __ATOMIC_RELAXED,
                                             __HIP_MEMORY_SCOPE_AGENT);
                bool ok = true;
#pragma unroll
                for (int j = 0; j < 16; ++j) {
                    ok = ok && (((unsigned)v[j] & 0xFFu) == want8)
                            && (((unsigned)(v[j] >> 32) & 0xFFu) == want8);
                }
                if (__all(ok)) break;
                __builtin_amdgcn_s_sleep(1);
            }
#pragma unroll
            for (int j = 0; j < 16; ++j) {
                float h0 = __uint_as_float((unsigned)v[j]);
                float h1 = __uint_as_float((unsigned)(v[j] >> 32));
                const int ko = blk * 32 + j * 2;
#pragma unroll
                for (int cg = 0; cg < 24; ++cg) {
                    acc[cg] = fmaf(h0, wp[cg][ko],     acc[cg]);
                    acc[cg] = fmaf(h1, wp[cg][ko + 1], acc[cg]);
                }
            }
        }

        // ---- LDS partial reduce (double-buffered, one barrier per step)
#pragma unroll
        for (int q = 0; q < 6; ++q) {
            float4 f4 = {acc[q * 4 + 0], acc[q * 4 + 1],
                         acc[q * 4 + 2], acc[q * 4 + 3]};
            *(float4*)&part[pp][w][q][lane][0] = f4;
        }
        __syncthreads();

        // ---- finalize my 2 (col,b) outputs
#pragma unroll
        for (int i = 0; i < 2; ++i) {
            const int cl = cl0 + i * 4;
            const int c  = c0 + cl;
            float ar = 0.f, az = 0.f, an = 0.f;
#pragma unroll
            for (int ww = 0; ww < 4; ++ww) {
                int cgr = cl * 3 + 0;
                ar += part[pp][ww][cgr >> 2][fb][cgr & 3];
                int cgz = cl * 3 + 1;
                az += part[pp][ww][cgz >> 2][fb][cgz & 3];
                int cgn = cl * 3 + 2;
                an += part[pp][ww][cgn >> 2][fb][cgn & 3];
            }
            float ghr = ar + bR[i], ghz = az + bZ[i], ghn = an + bN[i];
            float rr = 1.f / (1.f + expf(-(gr[i] + ghr)));
            float zz = 1.f / (1.f + expf(-(gz[i] + ghz)));
            float nn = tanhf(gn_[i] + rr * ghn);
            float hnew = (1.f - zz) * nn + zz * hprev[i];
            hprev[i] = hnew;

            // publish tagged dword (value + step tag in one atomic store)
            unsigned bits = (__float_as_uint(hnew) & 0xFFFFFF00u) | tagp;
            __hip_atomic_store(hwN + (size_t)(c >> 1) * 128 + fb * 2 + (c & 1),
                               bits, __ATOMIC_RELAXED, __HIP_MEMORY_SCOPE_AGENT);
            // clean value to the big output tensor
            out[(size_t)t * (BB * DD) + (size_t)fb * DD + dir * HH + c] = hnew;
        }
    }
}

// ---------------------------------------------------------------------------
// Attention logits: logits[b][t] += sum_n tanh(hidden[t,b,:]·fcw[n,:] + fcb[n]) * upw[n]
// ---------------------------------------------------------------------------
__global__ __launch_bounds__(256) void attn_logits(
    const float* __restrict__ Xh,   // hidden [T*B][768]
    const float* __restrict__ fcw,  // [768][768]
    const float* __restrict__ fcb, const float* __restrict__ upw,
    float* __restrict__ logits)     // [B][T]
{
    __shared__ float As[BK][TILE + 4];
    __shared__ float Bs[BK][TILE + 4];
    __shared__ float red[TILE][17];
    const int tid = threadIdx.x;
    const int tx = tid & 15, ty = tid >> 4;
    const int m0 = blockIdx.y * TILE;
    const int n0 = blockIdx.x * TILE;

    float acc[8][8];
#pragma unroll
    for (int i = 0; i < 8; i++)
#pragma unroll
        for (int j = 0; j < 8; j++) acc[i][j] = 0.f;

    for (int k0 = 0; k0 < 768; k0 += BK) {
#pragma unroll
        for (int l = 0; l < 2; l++) {
            int id = tid + l * 256;
            int r  = id >> 2;
            int kq = (id & 3) * 4;
            float4 v = *(const float4*)(Xh + (size_t)(m0 + r) * 768 + k0 + kq);
            As[kq + 0][r] = v.x; As[kq + 1][r] = v.y;
            As[kq + 2][r] = v.z; As[kq + 3][r] = v.w;
        }
#pragma unroll
        for (int l = 0; l < 2; l++) {
            int id = tid + l * 256;
            int r  = id >> 2;
            int kq = (id & 3) * 4;
            float4 v = *(const float4*)(fcw + (size_t)(n0 + r) * 768 + k0 + kq);
            Bs[kq + 0][r] = v.x; Bs[kq + 1][r] = v.y;
            Bs[kq + 2][r] = v.z; Bs[kq + 3][r] = v.w;
        }
        __syncthreads();
#pragma unroll
        for (int kk = 0; kk < BK; ++kk) {
            float av[8], bv[8];
            *(float4*)&av[0] = *(const float4*)&As[kk][ty * 8];
            *(float4*)&av[4] = *(const float4*)&As[kk][ty * 8 + 4];
            *(float4*)&bv[0] = *(const float4*)&Bs[kk][tx * 8];
            *(float4*)&bv[4] = *(const float4*)&Bs[kk][tx * 8 + 4];
#pragma unroll
            for (int i = 0; i < 8; i++)
#pragma unroll
                for (int j = 0; j < 8; j++)
                    acc[i][j] = fmaf(av[i], bv[j], acc[i][j]);
        }
        __syncthreads();
    }

#pragma unroll
    for (int i = 0; i < 8; i++) {
        float p = 0.f;
#pragma unroll
        for (int jj = 0; jj < 8; jj++) {
            int n = n0 + tx * 8 + jj;
            p += tanhf(acc[i][jj] + fcb[n]) * upw[n];
        }
        red[ty * 8 + i][tx] = p;
    }
    __syncthreads();
    if (tid < TILE) {
        float s = 0.f;
#pragma unroll
        for (int xk = 0; xk < 16; xk++) s += red[tid][xk];
        int m = m0 + tid;
        int t = m >> 6, b = m & 63;
        atomicAdd(&logits[(size_t)b * TT + t], s);
    }
}

// ---------------------------------------------------------------------------
// Softmax over T per batch + weighted pooling
// ---------------------------------------------------------------------------
__global__ __launch_bounds__(256) void softmax_pool(
    const float* __restrict__ logits, const float* __restrict__ upwb,
    const float* __restrict__ hidden, float* __restrict__ out)
{
    const int b = blockIdx.x, tid = threadIdx.x;
    __shared__ float sa[256];
    __shared__ float red[256];

    float l = logits[(size_t)b * TT + tid] + upwb[0];
    red[tid] = l; __syncthreads();
    for (int s = 128; s > 0; s >>= 1) {
        if (tid < s) red[tid] = fmaxf(red[tid], red[tid + s]);
        __syncthreads();
    }
    float mx = red[0];
    __syncthreads();
    float e = expf(l - mx);
    sa[tid] = e; red[tid] = e; __syncthreads();
    for (int s = 128; s > 0; s >>= 1) {
        if (tid < s) red[tid] += red[tid + s];
        __syncthreads();
    }
    float inv = 1.f / red[0];

    float o0 = 0.f, o1 = 0.f, o2 = 0.f;
    for (int t = 0; t < TT; t++) {
        float a = sa[t] * inv;
        const float* hp = hidden + (size_t)t * (BB * DD) + (size_t)b * DD;
        o0 = fmaf(a, hp[tid],       o0);
        o1 = fmaf(a, hp[tid + 256], o1);
        o2 = fmaf(a, hp[tid + 512], o2);
    }
    out[(size_t)b * DD + tid]       = o0;
    out[(size_t)b * DD + tid + 256] = o1;
    out[(size_t)b * DD + tid + 512] = o2;
}

// ---------------------------------------------------------------------------
extern "C" void kernel_launch(void* const* d_in, const int* in_sizes, int n_in,
                              void* d_out, int out_size, void* d_ws, size_t ws_size,
                              hipStream_t stream)
{
    const float* S        = (const float*)d_in[0];
    const float* w_ih_l0f = (const float*)d_in[1];
    const float* w_hh_l0f = (const float*)d_in[2];
    const float* b_ih_l0f = (const float*)d_in[3];
    const float* b_hh_l0f = (const float*)d_in[4];
    const float* w_ih_l0b = (const float*)d_in[5];
    const float* w_hh_l0b = (const float*)d_in[6];
    const float* b_ih_l0b = (const float*)d_in[7];
    const float* b_hh_l0b = (const float*)d_in[8];
    const float* w_ih_l1f = (const float*)d_in[9];
    const float* w_hh_l1f = (const float*)d_in[10];
    const float* b_ih_l1f = (const float*)d_in[11];
    const float* b_hh_l1f = (const float*)d_in[12];
    const float* w_ih_l1b = (const float*)d_in[13];
    const float* w_hh_l1b = (const float*)d_in[14];
    const float* b_ih_l1b = (const float*)d_in[15];
    const float* b_hh_l1b = (const float*)d_in[16];
    const float* fc_w     = (const float*)d_in[17];
    const float* fc_b     = (const float*)d_in[18];
    const float* upw_w    = (const float*)d_in[19];
    const float* upw_b    = (const float*)d_in[20];

    // workspace layout (floats)
    float* gxT     = (float*)d_ws;                       // 256*2304*64
    float* buf2    = gxT  + (size_t)TT * G6 * BB;        // 256*64*768
    unsigned* hv0  = (unsigned*)(buf2 + (size_t)TT * BB * DD);  // layer0: 98304 dw
    unsigned* hv1  = hv0 + 98304;                        // layer1: 98304 dw
    float* logits  = (float*)(hv1 + 98304);              // 64*256

    // zero both layers' h buffers + logits (contiguous region), every launch
    hipMemsetAsync(hv0, 0, (size_t)(2 * 98304 + 16384) * 4, stream);

    // layer 0 input gates
    gemm_gx<<<dim3(18, 128), 256, 0, stream>>>(S, 0, w_ih_l0f, w_ih_l0b,
                                               b_ih_l0f, b_ih_l0b, gxT);
    // layer 0 recurrence -> buf2
    {
        void* args[] = {(void*)&gxT, (void*)&w_hh_l0f, (void*)&w_hh_l0b,
                        (void*)&b_hh_l0f, (void*)&b_hh_l0b, (void*)&hv0,
                        (void*)&buf2};
        hipLaunchCooperativeKernel((const void*)recur9, dim3(96), dim3(256),
                                   args, 0, stream);
    }
    // layer 1 input gates (from buf2)
    gemm_gx<<<dim3(18, 128), 256, 0, stream>>>(buf2, 1, w_ih_l1f, w_ih_l1b,
                                               b_ih_l1f, b_ih_l1b, gxT);
    // layer 1 recurrence -> buf2 (separate h region, already zeroed)
    {
        void* args[] = {(void*)&gxT, (void*)&w_hh_l1f, (void*)&w_hh_l1b,
                        (void*)&b_hh_l1f, (void*)&b_hh_l1b, (void*)&hv1,
                        (void*)&buf2};
        hipLaunchCooperativeKernel((const void*)recur9, dim3(96), dim3(256),
                                   args, 0, stream);
    }
    // attention logits + pooling
    attn_logits<<<dim3(6, 128), 256, 0, stream>>>(buf2, fc_w, fc_b, upw_w, logits);
    softmax_pool<<<64, 256, 0, stream>>>(logits, upw_b, buf2, (float*)d_out);
}

// Round 9
// 7339.603 us; speedup vs baseline: 1.3626x; 1.3624x over previous
//
#include <hip/hip_runtime.h>

// Problem constants
#define BB   64      // batch
#define TT   256     // seq len
#define II   768     // input dim
#define HH   384     // hidden per direction
#define DD   768     // 2*HH
#define G3   1152    // 3*HH
#define G6   2304    // both directions' gates

#define TILE 128
#define BK   16

typedef unsigned long long u64t;

// ---------------------------------------------------------------------------
// GEMM: gxT[t][n][b] = bias[n] + sum_k X[t,b,k] * W[n,k]   (n in [0,2304))
// Transposed output (n-major, batch-minor): recurrence reads coalesced rows.
// xmode 0: X = Sentences [B][T][768]; xmode 1: X = [T*B][768] row-major.
// ---------------------------------------------------------------------------
__global__ __launch_bounds__(256) void gemm_gx(
    const float* __restrict__ X, int xmode,
    const float* __restrict__ wf, const float* __restrict__ wb,
    const float* __restrict__ bif, const float* __restrict__ bib,
    float* __restrict__ gx)
{
    __shared__ float As[BK][TILE + 4];
    __shared__ float Bs[BK][TILE + 4];
    const int tid = threadIdx.x;
    const int tx = tid & 15, ty = tid >> 4;
    const int m0 = blockIdx.y * TILE;
    const int n0 = blockIdx.x * TILE;

    float acc[8][8];
#pragma unroll
    for (int i = 0; i < 8; i++)
#pragma unroll
        for (int j = 0; j < 8; j++) acc[i][j] = 0.f;

    for (int k0 = 0; k0 < 768; k0 += BK) {
#pragma unroll
        for (int l = 0; l < 2; l++) {
            int id = tid + l * 256;          // 0..511
            int r  = id >> 2;                // 0..127
            int kq = (id & 3) * 4;
            int m  = m0 + r;
            const float* src;
            if (xmode == 0) {
                int b = m & 63, t = m >> 6;
                src = X + (size_t)b * (TT * II) + (size_t)t * II + k0 + kq;
            } else {
                src = X + (size_t)m * 768 + k0 + kq;
            }
            float4 v = *(const float4*)src;
            As[kq + 0][r] = v.x; As[kq + 1][r] = v.y;
            As[kq + 2][r] = v.z; As[kq + 3][r] = v.w;
        }
#pragma unroll
        for (int l = 0; l < 2; l++) {
            int id = tid + l * 256;
            int r  = id >> 2;
            int kq = (id & 3) * 4;
            int n  = n0 + r;
            const float* wsrc = (n < G3) ? (wf + (size_t)n * 768)
                                         : (wb + (size_t)(n - G3) * 768);
            float4 v = *(const float4*)(wsrc + k0 + kq);
            Bs[kq + 0][r] = v.x; Bs[kq + 1][r] = v.y;
            Bs[kq + 2][r] = v.z; Bs[kq + 3][r] = v.w;
        }
        __syncthreads();
#pragma unroll
        for (int kk = 0; kk < BK; ++kk) {
            float av[8], bv[8];
            *(float4*)&av[0] = *(const float4*)&As[kk][ty * 8];
            *(float4*)&av[4] = *(const float4*)&As[kk][ty * 8 + 4];
            *(float4*)&bv[0] = *(const float4*)&Bs[kk][tx * 8];
            *(float4*)&bv[4] = *(const float4*)&Bs[kk][tx * 8 + 4];
#pragma unroll
            for (int i = 0; i < 8; i++)
#pragma unroll
                for (int j = 0; j < 8; j++)
                    acc[i][j] = fmaf(av[i], bv[j], acc[i][j]);
        }
        __syncthreads();
    }

#pragma unroll
    for (int i = 0; i < 8; i++) {
        int m = m0 + ty * 8 + i;
        int t = m >> 6, b = m & 63;
        float* dst = gx + ((size_t)t * G6 + n0 + tx * 8) * 64 + b;
#pragma unroll
        for (int j = 0; j < 8; j++) {
            int n = n0 + tx * 8 + j;
            float bias = (n < G3) ? bif[n] : bib[n - G3];
            dst[(size_t)j * 64] = acc[i][j] + bias;
        }
    }
}

// ---------------------------------------------------------------------------
// Recurrent kernel v10: v5 geometry + mantissa-tagged dwords + 2 load blocks.
//
// h element (k,b) of a (dir,pp) buffer lives at dword (k>>1)*128 + b*2 +
// (k&1); its low 8 mantissa bits hold the step tag (rel err <= 2^-16).
// Producers publish bits=(h&0xFFFFFF00)|((s+1)&0xFF) with one relaxed
// agent-scope dword store. Consumers load u64s (2 consecutive k, coalesced
// 512 B/wave) and retry until ALL tags == s&0xFF. Race-free as in v5/v9:
// writes into buffer pn at step s happen only after validating all of pp at
// step s, which implies every WG finished reading pn at step s-1.
//
// 192 WGs x 256 thr: WG 0..95 fwd, 96..191 bwd; 4 cols/WG; wave w covers
// k-chunk [w*96,(w+1)*96) for all 12 (col,gate) dots in 2 blocks of 24 u64
// (2 L3 round trips/step), then finalizes col c0+w after the conflict-free
// LDS partial reduce (one __syncthreads per step, double-buffered).
// ---------------------------------------------------------------------------
__global__ __launch_bounds__(256) void recur10(
    const float* __restrict__ gxT,  // [T][2304][64] (b_ih already added)
    const float* __restrict__ whf, const float* __restrict__ whb,
    const float* __restrict__ bhf, const float* __restrict__ bhb,
    unsigned* __restrict__ hv,      // [2dir][2pp][192][64][2] dwords, zeroed
    float* __restrict__ out)        // [T][B][768]
{
    __shared__ float part[2][4][12][64];    // v5 layout: 0 bank conflicts

    const int bid  = blockIdx.x;            // 0..191
    const int dir  = bid / 96;
    const int c0   = (bid % 96) * 4;        // 4 columns per WG
    const int tid  = threadIdx.x;
    const int lane = tid & 63;              // batch
    const int w    = __builtin_amdgcn_readfirstlane(tid >> 6);  // wave 0..3
    const int c    = c0 + w;                // column this wave finalizes

    const float* wh = dir ? whb : whf;
    const float* bh = dir ? bhb : bhf;

    // 12 wave-uniform weight row pointers, offset to this wave's k-chunk
    const float* wp[12];
#pragma unroll
    for (int cc = 0; cc < 4; cc++)
#pragma unroll
        for (int g = 0; g < 3; g++)
            wp[cc * 3 + g] = wh + (size_t)(g * HH + c0 + cc) * HH + w * 96;

    const float bhr = bh[c], bhz = bh[HH + c], bhn = bh[2 * HH + c];

    float hprev = 0.f;

#pragma unroll 1
    for (int s = 0; s < TT; ++s) {
        const int t  = dir ? (TT - 1 - s) : s;
        const int pp = s & 1, pn = pp ^ 1;
        const u64t* hr  = (const u64t*)hv + (size_t)(dir * 2 + pp) * 12288;
        unsigned*   hwN = hv + (size_t)(dir * 2 + pn) * 24576;
        const unsigned want8 = (unsigned)s & 0xFFu;
        const unsigned tagp  = (unsigned)(s + 1) & 0xFFu;

        // gx prefetch for my column (coalesced, L2 path, consumed at end)
        const float* gA = gxT + ((size_t)t * G6 + dir * G3) * 64 + lane;
        float gr = gA[(size_t)(0 * HH + c) * 64];
        float gz = gA[(size_t)(1 * HH + c) * 64];
        float gn = gA[(size_t)(2 * HH + c) * 64];

        float acc[12];
#pragma unroll
        for (int i = 0; i < 12; i++) acc[i] = 0.f;

        // ---- consume: 2 blocks x 24 u64 (48 k each), retry until tags valid
#pragma unroll 1
        for (int blk = 0; blk < 2; ++blk) {
            const size_t base = (size_t)(w * 48 + blk * 24) * 64 + lane;
            u64t v[24];
            while (true) {
#pragma unroll
                for (int j = 0; j < 24; ++j)
                    v[j] = __hip_atomic_load(hr + base + (size_t)j * 64,
                                             __ATOMIC_RELAXED,
                                             __HIP_MEMORY_SCOPE_AGENT);
                bool ok = true;
#pragma unroll
                for (int j = 0; j < 24; ++j)
                    ok = ok && (((unsigned)v[j] & 0xFFu) == want8)
                            && (((unsigned)(v[j] >> 32) & 0xFFu) == want8);
                if (__all(ok)) break;
                __builtin_amdgcn_s_sleep(1);
            }
#pragma unroll
            for (int j = 0; j < 24; ++j) {
                float h0 = __uint_as_float((unsigned)v[j]);
                float h1 = __uint_as_float((unsigned)(v[j] >> 32));
                const int ko = blk * 48 + j * 2;
#pragma unroll
                for (int cg = 0; cg < 12; ++cg) {
                    acc[cg] = fmaf(h0, wp[cg][ko],     acc[cg]);
                    acc[cg] = fmaf(h1, wp[cg][ko + 1], acc[cg]);
                }
            }
        }

        // ---- LDS partial reduce (v5 conflict-free layout, one barrier)
#pragma unroll
        for (int cg = 0; cg < 12; ++cg)
            part[pp][w][cg][lane] = acc[cg];
        __syncthreads();

        const int d0 = w * 3;
        float ar = part[pp][0][d0 + 0][lane] + part[pp][1][d0 + 0][lane]
                 + part[pp][2][d0 + 0][lane] + part[pp][3][d0 + 0][lane];
        float az = part[pp][0][d0 + 1][lane] + part[pp][1][d0 + 1][lane]
                 + part[pp][2][d0 + 1][lane] + part[pp][3][d0 + 1][lane];
        float an = part[pp][0][d0 + 2][lane] + part[pp][1][d0 + 2][lane]
                 + part[pp][2][d0 + 2][lane] + part[pp][3][d0 + 2][lane];

        float ghr = ar + bhr, ghz = az + bhz, ghn = an + bhn;
        float rr  = 1.f / (1.f + expf(-(gr + ghr)));
        float zz  = 1.f / (1.f + expf(-(gz + ghz)));
        float nn  = tanhf(gn + rr * ghn);
        float hnew = (1.f - zz) * nn + zz * hprev;
        hprev = hnew;

        // ---- publish tagged dword (value + step tag, one atomic store)
        unsigned bits = (__float_as_uint(hnew) & 0xFFFFFF00u) | tagp;
        __hip_atomic_store(hwN + (size_t)(c >> 1) * 128 + lane * 2 + (c & 1),
                           bits, __ATOMIC_RELAXED, __HIP_MEMORY_SCOPE_AGENT);
        // clean value to the big output tensor
        out[(size_t)t * (BB * DD) + (size_t)lane * DD + dir * HH + c] = hnew;
    }
}

// ---------------------------------------------------------------------------
// Attention logits: logits[b][t] += sum_n tanh(hidden[t,b,:]·fcw[n,:] + fcb[n]) * upw[n]
// ---------------------------------------------------------------------------
__global__ __launch_bounds__(256) void attn_logits(
    const float* __restrict__ Xh,   // hidden [T*B][768]
    const float* __restrict__ fcw,  // [768][768]
    const float* __restrict__ fcb, const float* __restrict__ upw,
    float* __restrict__ logits)     // [B][T]
{
    __shared__ float As[BK][TILE + 4];
    __shared__ float Bs[BK][TILE + 4];
    __shared__ float red[TILE][17];
    const int tid = threadIdx.x;
    const int tx = tid & 15, ty = tid >> 4;
    const int m0 = blockIdx.y * TILE;
    const int n0 = blockIdx.x * TILE;

    float acc[8][8];
#pragma unroll
    for (int i = 0; i < 8; i++)
#pragma unroll
        for (int j = 0; j < 8; j++) acc[i][j] = 0.f;

    for (int k0 = 0; k0 < 768; k0 += BK) {
#pragma unroll
        for (int l = 0; l < 2; l++) {
            int id = tid + l * 256;
            int r  = id >> 2;
            int kq = (id & 3) * 4;
            float4 v = *(const float4*)(Xh + (size_t)(m0 + r) * 768 + k0 + kq);
            As[kq + 0][r] = v.x; As[kq + 1][r] = v.y;
            As[kq + 2][r] = v.z; As[kq + 3][r] = v.w;
        }
#pragma unroll
        for (int l = 0; l < 2; l++) {
            int id = tid + l * 256;
            int r  = id >> 2;
            int kq = (id & 3) * 4;
            float4 v = *(const float4*)(fcw + (size_t)(n0 + r) * 768 + k0 + kq);
            Bs[kq + 0][r] = v.x; Bs[kq + 1][r] = v.y;
            Bs[kq + 2][r] = v.z; Bs[kq + 3][r] = v.w;
        }
        __syncthreads();
#pragma unroll
        for (int kk = 0; kk < BK; ++kk) {
            float av[8], bv[8];
            *(float4*)&av[0] = *(const float4*)&As[kk][ty * 8];
            *(float4*)&av[4] = *(const float4*)&As[kk][ty * 8 + 4];
            *(float4*)&bv[0] = *(const float4*)&Bs[kk][tx * 8];
            *(float4*)&bv[4] = *(const float4*)&Bs[kk][tx * 8 + 4];
#pragma unroll
            for (int i = 0; i < 8; i++)
#pragma unroll
                for (int j = 0; j < 8; j++)
                    acc[i][j] = fmaf(av[i], bv[j], acc[i][j]);
        }
        __syncthreads();
    }

#pragma unroll
    for (int i = 0; i < 8; i++) {
        float p = 0.f;
#pragma unroll
        for (int jj = 0; jj < 8; jj++) {
            int n = n0 + tx * 8 + jj;
            p += tanhf(acc[i][jj] + fcb[n]) * upw[n];
        }
        red[ty * 8 + i][tx] = p;
    }
    __syncthreads();
    if (tid < TILE) {
        float s = 0.f;
#pragma unroll
        for (int xk = 0; xk < 16; xk++) s += red[tid][xk];
        int m = m0 + tid;
        int t = m >> 6, b = m & 63;
        atomicAdd(&logits[(size_t)b * TT + t], s);
    }
}

// ---------------------------------------------------------------------------
// Softmax over T per batch + weighted pooling
// ---------------------------------------------------------------------------
__global__ __launch_bounds__(256) void softmax_pool(
    const float* __restrict__ logits, const float* __restrict__ upwb,
    const float* __restrict__ hidden, float* __restrict__ out)
{
    const int b = blockIdx.x, tid = threadIdx.x;
    __shared__ float sa[256];
    __shared__ float red[256];

    float l = logits[(size_t)b * TT + tid] + upwb[0];
    red[tid] = l; __syncthreads();
    for (int s = 128; s > 0; s >>= 1) {
        if (tid < s) red[tid] = fmaxf(red[tid], red[tid + s]);
        __syncthreads();
    }
    float mx = red[0];
    __syncthreads();
    float e = expf(l - mx);
    sa[tid] = e; red[tid] = e; __syncthreads();
    for (int s = 128; s > 0; s >>= 1) {
        if (tid < s) red[tid] += red[tid + s];
        __syncthreads();
    }
    float inv = 1.f / red[0];

    float o0 = 0.f, o1 = 0.f, o2 = 0.f;
    for (int t = 0; t < TT; t++) {
        float a = sa[t] * inv;
        const float* hp = hidden + (size_t)t * (BB * DD) + (size_t)b * DD;
        o0 = fmaf(a, hp[tid],       o0);
        o1 = fmaf(a, hp[tid + 256], o1);
        o2 = fmaf(a, hp[tid + 512], o2);
    }
    out[(size_t)b * DD + tid]       = o0;
    out[(size_t)b * DD + tid + 256] = o1;
    out[(size_t)b * DD + tid + 512] = o2;
}

// ---------------------------------------------------------------------------
extern "C" void kernel_launch(void* const* d_in, const int* in_sizes, int n_in,
                              void* d_out, int out_size, void* d_ws, size_t ws_size,
                              hipStream_t stream)
{
    const float* S        = (const float*)d_in[0];
    const float* w_ih_l0f = (const float*)d_in[1];
    const float* w_hh_l0f = (const float*)d_in[2];
    const float* b_ih_l0f = (const float*)d_in[3];
    const float* b_hh_l0f = (const float*)d_in[4];
    const float* w_ih_l0b = (const float*)d_in[5];
    const float* w_hh_l0b = (const float*)d_in[6];
    const float* b_ih_l0b = (const float*)d_in[7];
    const float* b_hh_l0b = (const float*)d_in[8];
    const float* w_ih_l1f = (const float*)d_in[9];
    const float* w_hh_l1f = (const float*)d_in[10];
    const float* b_ih_l1f = (const float*)d_in[11];
    const float* b_hh_l1f = (const float*)d_in[12];
    const float* w_ih_l1b = (const float*)d_in[13];
    const float* w_hh_l1b = (const float*)d_in[14];
    const float* b_ih_l1b = (const float*)d_in[15];
    const float* b_hh_l1b = (const float*)d_in[16];
    const float* fc_w     = (const float*)d_in[17];
    const float* fc_b     = (const float*)d_in[18];
    const float* upw_w    = (const float*)d_in[19];
    const float* upw_b    = (const float*)d_in[20];

    // workspace layout (floats)
    float* gxT     = (float*)d_ws;                       // 256*2304*64
    float* buf2    = gxT  + (size_t)TT * G6 * BB;        // 256*64*768
    unsigned* hv0  = (unsigned*)(buf2 + (size_t)TT * BB * DD);  // layer0: 98304 dw
    unsigned* hv1  = hv0 + 98304;                        // layer1: 98304 dw
    float* logits  = (float*)(hv1 + 98304);              // 64*256

    // zero both layers' h buffers + logits (contiguous region), every launch
    hipMemsetAsync(hv0, 0, (size_t)(2 * 98304 + 16384) * 4, stream);

    // layer 0 input gates
    gemm_gx<<<dim3(18, 128), 256, 0, stream>>>(S, 0, w_ih_l0f, w_ih_l0b,
                                               b_ih_l0f, b_ih_l0b, gxT);
    // layer 0 recurrence -> buf2
    {
        void* args[] = {(void*)&gxT, (void*)&w_hh_l0f, (void*)&w_hh_l0b,
                        (void*)&b_hh_l0f, (void*)&b_hh_l0b, (void*)&hv0,
                        (void*)&buf2};
        hipLaunchCooperativeKernel((const void*)recur10, dim3(192), dim3(256),
                                   args, 0, stream);
    }
    // layer 1 input gates (from buf2)
    gemm_gx<<<dim3(18, 128), 256, 0, stream>>>(buf2, 1, w_ih_l1f, w_ih_l1b,
                                               b_ih_l1f, b_ih_l1b, gxT);
    // layer 1 recurrence -> buf2 (separate h region, already zeroed)
    {
        void* args[] = {(void*)&gxT, (void*)&w_hh_l1f, (void*)&w_hh_l1b,
                        (void*)&b_hh_l1f, (void*)&b_hh_l1b, (void*)&hv1,
                        (void*)&buf2};
        hipLaunchCooperativeKernel((const void*)recur10, dim3(192), dim3(256),
                                   args, 0, stream);
    }
    // attention logits + pooling
    attn_logits<<<dim3(6, 128), 256, 0, stream>>>(buf2, fc_w, fc_b, upw_w, logits);
    softmax_pool<<<64, 256, 0, stream>>>(logits, upw_b, buf2, (float*)d_out);
}